// Round 2
// baseline (2766.618 us; speedup 1.0000x reference)
//
#include <hip/hip_runtime.h>
#include <hip/hip_bf16.h>

#define B_ 128
#define T_ 512
#define BIN_ 24
#define D_ 256
#define S_ 128
#define L_ 2
#define BT_ (B_*T_)

typedef __hip_bfloat16 bf16;
typedef __hip_bfloat162 bf162;

__device__ __forceinline__ float b2f(bf16 x){ return __bfloat162float(x); }
__device__ __forceinline__ bf16 f2b(float x){ return __float2bfloat16(x); }

// ---------------- tables: sinusoid PE (scaled) + rope sin/cos ----------------
__global__ void tables_kernel(const float* pe_scale_ptr, float* pe_tab, float* rs, float* rc) {
  int t = blockIdx.x;      // 0..511
  int j = threadIdx.x;     // 64 threads
  float ps = pe_scale_ptr[0];
  const float LOG1E4 = 9.210340371976184f;
  if (j < 64) {
    float inv = expf(-LOG1E4 * (float)j / 64.f);   // rope: 10000^(-2j/128)
    float ang = (float)t * inv;
    rs[t*64 + j] = sinf(ang);
    rc[t*64 + j] = cosf(ang);
  }
  if (j < BIN_) {
    int jj = (j < 12) ? j : (j - 12);
    float inv = expf(-LOG1E4 * (float)jj / 11.f);  // sinusoid: num=12, denom num-1
    float ang = (float)t * inv;
    pe_tab[t*BIN_ + j] = ps * ((j < 12) ? sinf(ang) : cosf(ang));
  }
}

// ---------------- embed: h = swish((x + pe) @ W_in + b_in) ----------------
__global__ __launch_bounds__(256) void embed_kernel(const float* x, const float* pe_tab,
                const float* W_in, const float* b_in, float* h) {
  __shared__ float xr[8][BIN_];
  int tid = threadIdx.x;
  int row0 = blockIdx.x * 8;
  if (tid < 8*BIN_) {
    int r = tid / BIN_, k = tid % BIN_;
    int row = row0 + r;
    int t = row & (T_-1);
    xr[r][k] = x[(size_t)row*BIN_ + k] + pe_tab[t*BIN_ + k];
  }
  __syncthreads();
  int d = tid;
  float bi = b_in[d];
  float acc[8];
  #pragma unroll
  for (int r=0;r<8;r++) acc[r]=bi;
  #pragma unroll
  for (int k=0;k<BIN_;k++){
    float w = W_in[k*D_ + d];
    #pragma unroll
    for (int r=0;r<8;r++) acc[r] += xr[r][k]*w;
  }
  #pragma unroll
  for (int r=0;r<8;r++){
    float v = acc[r];
    h[(size_t)(row0+r)*D_ + d] = v / (1.f + expf(-v));
  }
}

// ---------------- rms: per-row rsqrt(mean(h^2)+eps)*norm_scale[l] ----------------
__global__ __launch_bounds__(256) void rms_kernel(const float* h, const float* norm_scale,
                                                  int l, float* rms) {
  int tid = threadIdx.x;
  int lane = tid & 63;
  size_t row = (size_t)blockIdx.x*4 + (tid>>6);
  float4 hv = *((const float4*)(h + row*D_) + lane);
  float s = hv.x*hv.x + hv.y*hv.y + hv.z*hv.z + hv.w*hv.w;
  #pragma unroll
  for (int off=32; off>0; off>>=1) s += __shfl_down(s, off);
  if (lane==0) rms[row] = rsqrtf(s*(1.f/D_) + 1e-6f) * norm_scale[l];
}

// ---------------- gemm1: uv = swish((rms.*h) @ W1 + b1), N=640, bf16 out ----------------
__global__ __launch_bounds__(256) void gemm1_kernel(const float* A, const float* rms,
      const float* Bw, const float* bias, bf16* Cout) {
  __shared__ float As[16][65];
  __shared__ float Bs[16][68];
  int tid = threadIdx.x;
  int row0 = blockIdx.x*64, col0 = blockIdx.y*64;
  int tx = tid & 15, ty = tid >> 4;
  int ar = tid >> 2, akq = (tid & 3)*4;
  int bk = tid >> 4, bn = (tid & 15)*4;
  float ascale = rms[row0 + ar];
  float acc[4][4] = {};
  for (int k0=0; k0<D_; k0+=16) {
    float4 av = *(const float4*)(A + (size_t)(row0+ar)*D_ + k0 + akq);
    As[akq+0][ar]=av.x*ascale; As[akq+1][ar]=av.y*ascale;
    As[akq+2][ar]=av.z*ascale; As[akq+3][ar]=av.w*ascale;
    float4 bv = *(const float4*)(Bw + (size_t)(k0+bk)*640 + col0 + bn);
    Bs[bk][bn+0]=bv.x; Bs[bk][bn+1]=bv.y; Bs[bk][bn+2]=bv.z; Bs[bk][bn+3]=bv.w;
    __syncthreads();
    #pragma unroll
    for (int kk=0; kk<16; kk++){
      float a0=As[kk][ty*4+0],a1=As[kk][ty*4+1],a2=As[kk][ty*4+2],a3=As[kk][ty*4+3];
      float b0=Bs[kk][tx*4+0],b1=Bs[kk][tx*4+1],b2v=Bs[kk][tx*4+2],b3=Bs[kk][tx*4+3];
      acc[0][0]+=a0*b0; acc[0][1]+=a0*b1; acc[0][2]+=a0*b2v; acc[0][3]+=a0*b3;
      acc[1][0]+=a1*b0; acc[1][1]+=a1*b1; acc[1][2]+=a1*b2v; acc[1][3]+=a1*b3;
      acc[2][0]+=a2*b0; acc[2][1]+=a2*b1; acc[2][2]+=a2*b2v; acc[2][3]+=a2*b3;
      acc[3][0]+=a3*b0; acc[3][1]+=a3*b1; acc[3][2]+=a3*b2v; acc[3][3]+=a3*b3;
    }
    __syncthreads();
  }
  #pragma unroll
  for (int i=0;i<4;i++)
    #pragma unroll
    for (int j=0;j<4;j++){
      size_t r = row0 + ty*4 + i;
      int c = col0 + tx*4 + j;
      float v = acc[i][j] + bias[c];
      Cout[r*640 + c] = f2b(v / (1.f + expf(-v)));
    }
}

// ---------------- gemm2: h += ou @ W2 + b2, N=256 ----------------
__global__ __launch_bounds__(256) void gemm2_kernel(const bf16* A, const float* Bw,
      const float* bias, float* h) {
  __shared__ float As[16][65];
  __shared__ float Bs[16][68];
  int tid = threadIdx.x;
  int row0 = blockIdx.x*64, col0 = blockIdx.y*64;
  int tx = tid & 15, ty = tid >> 4;
  int ar = tid >> 2, akq = (tid & 3)*4;
  int bk = tid >> 4, bn = (tid & 15)*4;
  float acc[4][4] = {};
  for (int k0=0; k0<D_; k0+=16) {
    const bf16* ap = A + (size_t)(row0+ar)*D_ + k0 + akq;
    As[akq+0][ar]=b2f(ap[0]); As[akq+1][ar]=b2f(ap[1]);
    As[akq+2][ar]=b2f(ap[2]); As[akq+3][ar]=b2f(ap[3]);
    float4 bv = *(const float4*)(Bw + (size_t)(k0+bk)*D_ + col0 + bn);
    Bs[bk][bn+0]=bv.x; Bs[bk][bn+1]=bv.y; Bs[bk][bn+2]=bv.z; Bs[bk][bn+3]=bv.w;
    __syncthreads();
    #pragma unroll
    for (int kk=0; kk<16; kk++){
      float a0=As[kk][ty*4+0],a1=As[kk][ty*4+1],a2=As[kk][ty*4+2],a3=As[kk][ty*4+3];
      float b0=Bs[kk][tx*4+0],b1=Bs[kk][tx*4+1],b2v=Bs[kk][tx*4+2],b3=Bs[kk][tx*4+3];
      acc[0][0]+=a0*b0; acc[0][1]+=a0*b1; acc[0][2]+=a0*b2v; acc[0][3]+=a0*b3;
      acc[1][0]+=a1*b0; acc[1][1]+=a1*b1; acc[1][2]+=a1*b2v; acc[1][3]+=a1*b3;
      acc[2][0]+=a2*b0; acc[2][1]+=a2*b1; acc[2][2]+=a2*b2v; acc[2][3]+=a2*b3;
      acc[3][0]+=a3*b0; acc[3][1]+=a3*b1; acc[3][2]+=a3*b2v; acc[3][3]+=a3*b3;
    }
    __syncthreads();
  }
  #pragma unroll
  for (int i=0;i<4;i++)
    #pragma unroll
    for (int j=0;j<4;j++){
      size_t r = row0 + ty*4 + i;
      int c = col0 + tx*4 + j;
      h[r*D_ + c] += acc[i][j] + bias[c];
    }
}

// ---------------- qk: rope(base*gamma+beta) for q and k ----------------
__global__ __launch_bounds__(256) void qk_kernel(const bf16* uv, const float* gamma, const float* beta,
      int l, const float* rs, const float* rc, bf16* q, bf16* k) {
  int tid = threadIdx.x;
  int j = tid & 127;
  size_t row = (size_t)blockIdx.x*2 + (tid>>7);
  int t = (int)(row & (T_-1));
  int j2 = j ^ 64;
  float v0 = b2f(uv[row*640 + 512 + j]);
  float v1 = b2f(uv[row*640 + 512 + j2]);
  int jm = j & 63;
  float sn = rs[t*64 + jm], cs = rc[t*64 + jm];
  float sgn = (j < 64) ? -1.f : 1.f;
  const float* g  = gamma + l*2*S_;
  const float* bt = beta  + l*2*S_;
  float xq = v0*g[j]      + bt[j];
  float pq = v1*g[j2]     + bt[j2];
  q[row*S_ + j] = f2b(xq*cs + sgn*pq*sn);
  float xk = v0*g[S_+j]   + bt[S_+j];
  float pk = v1*g[S_+j2]  + bt[S_+j2];
  k[row*S_ + j] = f2b(xk*cs + sgn*pk*sn);
}

// ---------------- attn: ou = u * ( relu(qk^T/512)^2 @ v ) fused ----------------
__global__ __launch_bounds__(256) void attn_kernel(const bf16* q, const bf16* k,
      const bf16* uv, bf16* ou) {
  __shared__ float qs[32][S_+4];
  __shared__ float ks[32][S_+4];
  __shared__ bf162 vs[32][128];
  __shared__ float ws[32][33];
  int tid = threadIdx.x;
  int b  = blockIdx.x >> 4;
  int nt = blockIdx.x & 15;
  size_t rowbase = (size_t)b*T_;
  int n0 = nt*32;
  for (int i=0;i<16;i++){
    int idx = i*256 + tid; int r = idx>>7, c = idx&127;
    qs[r][c] = b2f(q[(rowbase+n0+r)*S_ + c]);
  }
  const bf162* uv2 = (const bf162*)uv;
  int wr = tid>>3, wp = tid&7;
  float acc[32] = {};
  for (int m0=0; m0<T_; m0+=32) {
    __syncthreads();
    for (int i=0;i<16;i++){
      int idx = i*256 + tid; int r = idx>>7, c = idx&127;
      ks[r][c] = b2f(k[(rowbase+m0+r)*S_ + c]);
      vs[r][c] = uv2[(rowbase+m0+r)*320 + 128 + c];   // v slice cols 256..511
    }
    __syncthreads();
    float d0=0,d1=0,d2=0,d3=0;
    int n = wr, m = wp;
    for (int dd=0; dd<S_; dd++){
      float qv = qs[n][dd];
      d0 += qv*ks[m   ][dd];
      d1 += qv*ks[m+ 8][dd];
      d2 += qv*ks[m+16][dd];
      d3 += qv*ks[m+24][dd];
    }
    const float sc = 1.f/512.f;
    float t0=fmaxf(d0*sc,0.f), t1=fmaxf(d1*sc,0.f), t2=fmaxf(d2*sc,0.f), t3=fmaxf(d3*sc,0.f);
    ws[n][m]=t0*t0; ws[n][m+8]=t1*t1; ws[n][m+16]=t2*t2; ws[n][m+24]=t3*t3;
    __syncthreads();
    #pragma unroll 4
    for (int mm=0; mm<32; mm++){
      float w = ws[wr][mm];
      #pragma unroll
      for (int cc=0; cc<16; cc++){
        bf162 v2 = vs[mm][wp + 8*cc];
        acc[2*cc]   += w * b2f(v2.x);
        acc[2*cc+1] += w * b2f(v2.y);
      }
    }
  }
  size_t orow = rowbase + n0 + wr;
  bf162* ou2 = (bf162*)ou;
  #pragma unroll
  for (int cc=0; cc<16; cc++){
    bf162 u2 = uv2[orow*320 + wp + 8*cc];            // u slice cols 0..255
    bf162 o;
    o.x = f2b(acc[2*cc]   * b2f(u2.x));
    o.y = f2b(acc[2*cc+1] * b2f(u2.y));
    ou2[orow*128 + wp + 8*cc] = o;
  }
}

// ---------------- pooling, embedding, copyout ----------------
__global__ __launch_bounds__(256) void pool_kernel(const float* h, float* pooled) {
  int b = blockIdx.x, d = threadIdx.x;
  float s = 0.f;
  for (int t=0;t<T_;t++){
    float v = fmaxf(h[((size_t)b*T_+t)*D_ + d], 1e-6f);
    s += v*v*v;
  }
  pooled[b*D_+d] = cbrtf(s*(1.f/T_));
}

__global__ __launch_bounds__(256) void emb_kernel(const float* pooled, const float* We,
      const float* be, float* out) {
  __shared__ float pr[D_];
  __shared__ float red[256];
  int b = blockIdx.x, j = threadIdx.x;
  pr[j] = pooled[b*D_+j];
  __syncthreads();
  float acc = be[j];
  for (int kk=0;kk<D_;kk++) acc += pr[kk]*We[kk*D_+j];
  red[j] = acc*acc;
  __syncthreads();
  for (int off=128; off>0; off>>=1){
    if (j<off) red[j]+=red[j+off];
    __syncthreads();
  }
  out[b*D_+j] = acc * rsqrtf(red[0]);
}

__global__ __launch_bounds__(256) void copyout_kernel(const float* h, float* out) {
  size_t i = (size_t)blockIdx.x*256 + threadIdx.x;
  ((float4*)out)[i] = ((const float4*)h)[i];
}

extern "C" void kernel_launch(void* const* d_in, const int* in_sizes, int n_in,
                              void* d_out, int out_size, void* d_ws, size_t ws_size,
                              hipStream_t stream) {
  const float* x         = (const float*)d_in[0];
  const float* pe_scale  = (const float*)d_in[1];
  const float* W_in      = (const float*)d_in[2];
  const float* b_in      = (const float*)d_in[3];
  const float* norm_scale= (const float*)d_in[4];
  const float* W1        = (const float*)d_in[5];
  const float* b1        = (const float*)d_in[6];
  const float* gamma     = (const float*)d_in[7];
  const float* beta      = (const float*)d_in[8];
  const float* W2        = (const float*)d_in[9];
  const float* b2        = (const float*)d_in[10];
  const float* We        = (const float*)d_in[11];
  const float* be        = (const float*)d_in[12];

  char* ws = (char*)d_ws;
  float* h      = (float*)(ws);                       // 67,108,864 B
  bf16*  uv     = (bf16*)(ws + 67108864);             // 83,886,080 B
  bf16*  q      = (bf16*)(ws + 150994944);            // 16,777,216 B
  bf16*  kbuf   = (bf16*)(ws + 167772160);            // 16,777,216 B
  bf16*  ou     = (bf16*)(ws + 184549376);            // 33,554,432 B
  float* rms    = (float*)(ws + 218103808);           //    262,144 B
  float* pe_tab = (float*)(ws + 218365952);           //     49,152 B
  float* rs_tab = (float*)(ws + 218415104);           //    131,072 B
  float* rc_tab = (float*)(ws + 218546176);           //    131,072 B
  float* pooled = (float*)(ws + 218677248);           //    131,072 B

  tables_kernel<<<T_, 64, 0, stream>>>(pe_scale, pe_tab, rs_tab, rc_tab);
  embed_kernel<<<BT_/8, 256, 0, stream>>>(x, pe_tab, W_in, b_in, h);
  for (int l=0; l<L_; l++) {
    rms_kernel<<<BT_/4, 256, 0, stream>>>(h, norm_scale, l, rms);
    dim3 g1(BT_/64, 10);
    gemm1_kernel<<<g1, 256, 0, stream>>>(h, rms, W1 + (size_t)l*D_*640, b1 + l*640, uv);
    qk_kernel<<<BT_/2, 256, 0, stream>>>(uv, gamma, beta, l, rs_tab, rc_tab, q, kbuf);
    attn_kernel<<<B_*16, 256, 0, stream>>>(q, kbuf, uv, ou);
    dim3 g2(BT_/64, 4);
    gemm2_kernel<<<g2, 256, 0, stream>>>(ou, W2 + (size_t)l*D_*D_, b2 + l*D_, h);
  }
  pool_kernel<<<B_, 256, 0, stream>>>(h, pooled);
  emb_kernel<<<B_, 256, 0, stream>>>(pooled, We, be, (float*)d_out);
  copyout_kernel<<<BT_*D_/1024, 256, 0, stream>>>(h, (float*)d_out + B_*D_);
}

// Round 3
// 1457.941 us; speedup vs baseline: 1.8976x; 1.8976x over previous
//
#include <hip/hip_runtime.h>
#include <hip/hip_bf16.h>

#define B_ 128
#define T_ 512
#define BIN_ 24
#define D_ 256
#define S_ 128
#define L_ 2
#define BT_ (B_*T_)

typedef __hip_bfloat16 bf16;
typedef __hip_bfloat162 bf162;
typedef __attribute__((ext_vector_type(8))) short bf16x8;
typedef __attribute__((ext_vector_type(4))) float f32x4;

__device__ __forceinline__ float b2f(bf16 x){ return __bfloat162float(x); }
__device__ __forceinline__ bf16 f2b(float x){ return __float2bfloat16(x); }

// ---------------- tables: sinusoid PE (scaled) + rope sin/cos ----------------
__global__ void tables_kernel(const float* pe_scale_ptr, float* pe_tab, float* rs, float* rc) {
  int t = blockIdx.x;      // 0..511
  int j = threadIdx.x;     // 64 threads
  float ps = pe_scale_ptr[0];
  const float LOG1E4 = 9.210340371976184f;
  if (j < 64) {
    float inv = expf(-LOG1E4 * (float)j / 64.f);   // rope: 10000^(-2j/128)
    float ang = (float)t * inv;
    rs[t*64 + j] = sinf(ang);
    rc[t*64 + j] = cosf(ang);
  }
  if (j < BIN_) {
    int jj = (j < 12) ? j : (j - 12);
    float inv = expf(-LOG1E4 * (float)jj / 11.f);  // sinusoid: num=12, denom num-1
    float ang = (float)t * inv;
    pe_tab[t*BIN_ + j] = ps * ((j < 12) ? sinf(ang) : cosf(ang));
  }
}

// ---------------- embed: h = swish((x + pe) @ W_in + b_in) ----------------
__global__ __launch_bounds__(256) void embed_kernel(const float* x, const float* pe_tab,
                const float* W_in, const float* b_in, float* h) {
  __shared__ float xr[8][BIN_];
  int tid = threadIdx.x;
  int row0 = blockIdx.x * 8;
  if (tid < 8*BIN_) {
    int r = tid / BIN_, k = tid % BIN_;
    int row = row0 + r;
    int t = row & (T_-1);
    xr[r][k] = x[(size_t)row*BIN_ + k] + pe_tab[t*BIN_ + k];
  }
  __syncthreads();
  int d = tid;
  float bi = b_in[d];
  float acc[8];
  #pragma unroll
  for (int r=0;r<8;r++) acc[r]=bi;
  #pragma unroll
  for (int k=0;k<BIN_;k++){
    float w = W_in[k*D_ + d];
    #pragma unroll
    for (int r=0;r<8;r++) acc[r] += xr[r][k]*w;
  }
  #pragma unroll
  for (int r=0;r<8;r++){
    float v = acc[r];
    h[(size_t)(row0+r)*D_ + d] = v / (1.f + expf(-v));
  }
}

// ---------------- rms: per-row rsqrt(mean(h^2)+eps)*norm_scale[l] ----------------
__global__ __launch_bounds__(256) void rms_kernel(const float* h, const float* norm_scale,
                                                  int l, float* rms) {
  int tid = threadIdx.x;
  int lane = tid & 63;
  size_t row = (size_t)blockIdx.x*4 + (tid>>6);
  float4 hv = *((const float4*)(h + row*D_) + lane);
  float s = hv.x*hv.x + hv.y*hv.y + hv.z*hv.z + hv.w*hv.w;
  #pragma unroll
  for (int off=32; off>0; off>>=1) s += __shfl_down(s, off);
  if (lane==0) rms[row] = rsqrtf(s*(1.f/D_) + 1e-6f) * norm_scale[l];
}

// ---------------- gemm1: uv = swish((rms.*h) @ W1 + b1), N=640, bf16 out ----------------
__global__ __launch_bounds__(256) void gemm1_kernel(const float* A, const float* rms,
      const float* Bw, const float* bias, bf16* Cout) {
  __shared__ float As[16][65];
  __shared__ float Bs[16][68];
  int tid = threadIdx.x;
  int row0 = blockIdx.x*64, col0 = blockIdx.y*64;
  int tx = tid & 15, ty = tid >> 4;
  int ar = tid >> 2, akq = (tid & 3)*4;
  int bk = tid >> 4, bn = (tid & 15)*4;
  float ascale = rms[row0 + ar];
  float acc[4][4] = {};
  for (int k0=0; k0<D_; k0+=16) {
    float4 av = *(const float4*)(A + (size_t)(row0+ar)*D_ + k0 + akq);
    As[akq+0][ar]=av.x*ascale; As[akq+1][ar]=av.y*ascale;
    As[akq+2][ar]=av.z*ascale; As[akq+3][ar]=av.w*ascale;
    float4 bv = *(const float4*)(Bw + (size_t)(k0+bk)*640 + col0 + bn);
    Bs[bk][bn+0]=bv.x; Bs[bk][bn+1]=bv.y; Bs[bk][bn+2]=bv.z; Bs[bk][bn+3]=bv.w;
    __syncthreads();
    #pragma unroll
    for (int kk=0; kk<16; kk++){
      float a0=As[kk][ty*4+0],a1=As[kk][ty*4+1],a2=As[kk][ty*4+2],a3=As[kk][ty*4+3];
      float b0=Bs[kk][tx*4+0],b1=Bs[kk][tx*4+1],b2v=Bs[kk][tx*4+2],b3=Bs[kk][tx*4+3];
      acc[0][0]+=a0*b0; acc[0][1]+=a0*b1; acc[0][2]+=a0*b2v; acc[0][3]+=a0*b3;
      acc[1][0]+=a1*b0; acc[1][1]+=a1*b1; acc[1][2]+=a1*b2v; acc[1][3]+=a1*b3;
      acc[2][0]+=a2*b0; acc[2][1]+=a2*b1; acc[2][2]+=a2*b2v; acc[2][3]+=a2*b3;
      acc[3][0]+=a3*b0; acc[3][1]+=a3*b1; acc[3][2]+=a3*b2v; acc[3][3]+=a3*b3;
    }
    __syncthreads();
  }
  #pragma unroll
  for (int i=0;i<4;i++)
    #pragma unroll
    for (int j=0;j<4;j++){
      size_t r = row0 + ty*4 + i;
      int c = col0 + tx*4 + j;
      float v = acc[i][j] + bias[c];
      Cout[r*640 + c] = f2b(v / (1.f + expf(-v)));
    }
}

// ---------------- gemm2: h += ou @ W2 + b2, N=256 ----------------
__global__ __launch_bounds__(256) void gemm2_kernel(const bf16* A, const float* Bw,
      const float* bias, float* h) {
  __shared__ float As[16][65];
  __shared__ float Bs[16][68];
  int tid = threadIdx.x;
  int row0 = blockIdx.x*64, col0 = blockIdx.y*64;
  int tx = tid & 15, ty = tid >> 4;
  int ar = tid >> 2, akq = (tid & 3)*4;
  int bk = tid >> 4, bn = (tid & 15)*4;
  float acc[4][4] = {};
  for (int k0=0; k0<D_; k0+=16) {
    const bf16* ap = A + (size_t)(row0+ar)*D_ + k0 + akq;
    As[akq+0][ar]=b2f(ap[0]); As[akq+1][ar]=b2f(ap[1]);
    As[akq+2][ar]=b2f(ap[2]); As[akq+3][ar]=b2f(ap[3]);
    float4 bv = *(const float4*)(Bw + (size_t)(k0+bk)*D_ + col0 + bn);
    Bs[bk][bn+0]=bv.x; Bs[bk][bn+1]=bv.y; Bs[bk][bn+2]=bv.z; Bs[bk][bn+3]=bv.w;
    __syncthreads();
    #pragma unroll
    for (int kk=0; kk<16; kk++){
      float a0=As[kk][ty*4+0],a1=As[kk][ty*4+1],a2=As[kk][ty*4+2],a3=As[kk][ty*4+3];
      float b0=Bs[kk][tx*4+0],b1=Bs[kk][tx*4+1],b2v=Bs[kk][tx*4+2],b3=Bs[kk][tx*4+3];
      acc[0][0]+=a0*b0; acc[0][1]+=a0*b1; acc[0][2]+=a0*b2v; acc[0][3]+=a0*b3;
      acc[1][0]+=a1*b0; acc[1][1]+=a1*b1; acc[1][2]+=a1*b2v; acc[1][3]+=a1*b3;
      acc[2][0]+=a2*b0; acc[2][1]+=a2*b1; acc[2][2]+=a2*b2v; acc[2][3]+=a2*b3;
      acc[3][0]+=a3*b0; acc[3][1]+=a3*b1; acc[3][2]+=a3*b2v; acc[3][3]+=a3*b3;
    }
    __syncthreads();
  }
  #pragma unroll
  for (int i=0;i<4;i++)
    #pragma unroll
    for (int j=0;j<4;j++){
      size_t r = row0 + ty*4 + i;
      int c = col0 + tx*4 + j;
      h[r*D_ + c] += acc[i][j] + bias[c];
    }
}

// ---------------- qk: rope(base*gamma+beta) for q and k ----------------
__global__ __launch_bounds__(256) void qk_kernel(const bf16* uv, const float* gamma, const float* beta,
      int l, const float* rs, const float* rc, bf16* q, bf16* k) {
  int tid = threadIdx.x;
  int j = tid & 127;
  size_t row = (size_t)blockIdx.x*2 + (tid>>7);
  int t = (int)(row & (T_-1));
  int j2 = j ^ 64;
  float v0 = b2f(uv[row*640 + 512 + j]);
  float v1 = b2f(uv[row*640 + 512 + j2]);
  int jm = j & 63;
  float sn = rs[t*64 + jm], cs = rc[t*64 + jm];
  float sgn = (j < 64) ? -1.f : 1.f;
  const float* g  = gamma + l*2*S_;
  const float* bt = beta  + l*2*S_;
  float xq = v0*g[j]      + bt[j];
  float pq = v1*g[j2]     + bt[j2];
  q[row*S_ + j] = f2b(xq*cs + sgn*pq*sn);
  float xk = v0*g[S_+j]   + bt[S_+j];
  float pk = v1*g[S_+j2]  + bt[S_+j2];
  k[row*S_ + j] = f2b(xk*cs + sgn*pk*sn);
}

// ---------------- attn (MFMA): ou = u * ( relu(qk^T/512)^2 @ v ) ----------------
// Block: 4 waves, 64 Q-rows. K in padded LDS, V transposed+swizzled in LDS,
// P bounced through LDS per-wave, O bounced through LDS for coalesced u-mult.
__global__ __launch_bounds__(256) void attn_mfma_kernel(const bf16* q, const bf16* k,
      const bf16* uv, bf16* ou) {
  __shared__ char smem[59392];
  bf16* Ks = (bf16*)smem;            // [64][136]  (+8 pad -> floor-conflict b128 col reads)
  bf16* Vt = (bf16*)(smem + 17408);  // [256 e][64 m], 16B chunks XOR-swizzled by e&7; reused as Os[64][256]
  bf16* Ps = (bf16*)(smem + 50176);  // [64][72]

  int tid = threadIdx.x;
  int w = tid >> 6, l = tid & 63;
  int r = l & 15, g = l >> 4;
  int b  = blockIdx.x >> 3;
  int nt = blockIdx.x & 7;
  size_t rowbase = (size_t)b * T_;
  int n0 = nt * 64;

  // Q A-frags once from global: A[row=l&15][k=(l>>4)*8+j]
  bf16x8 qf[4];
  const bf16* qrow = q + (rowbase + n0 + 16*w + r) * S_ + g*8;
  #pragma unroll
  for (int kk=0; kk<4; kk++) qf[kk] = *(const bf16x8*)(qrow + kk*32);

  f32x4 oacc[16];
  #pragma unroll
  for (int i=0;i<16;i++) oacc[i] = (f32x4){0.f,0.f,0.f,0.f};

  for (int m0 = 0; m0 < T_; m0 += 64) {
    // ---- stage K tile (coalesced 16B loads, floor-conflict b128 writes) ----
    #pragma unroll
    for (int i=0;i<4;i++){
      int chunk = i*256 + tid;
      int row = chunk >> 4, c = chunk & 15;
      bf16x8 kv = *(const bf16x8*)(k + (rowbase + m0 + row)*S_ + c*8);
      *(bf16x8*)(Ks + row*136 + c*8) = kv;
    }
    // ---- stage V transposed+swizzled: thread loads V[m][8c..8c+7] coalesced,
    //      scatters 8 bf16 (rotated order so e&7 varies across lanes) ----
    #pragma unroll
    for (int i=0;i<8;i++){
      int chunk = i*256 + tid;
      int row = chunk >> 5, c = chunk & 31;
      bf16x8 vv = *(const bf16x8*)(uv + (rowbase + m0 + row)*640 + 256 + c*8);
      int mc = row >> 3, mo = row & 7;
      #pragma unroll
      for (int s=0;s<8;s++){
        int j = (s + (l & 7)) & 7;
        Vt[(8*c + j)*64 + ((mc ^ j) << 3) + mo] = ((bf16*)&vv)[j];
      }
    }
    __syncthreads();

    // ---- QK^T: rows 16w..16w+15 x cols m0..m0+63; P=relu(s/512)^2 -> Ps ----
    #pragma unroll
    for (int nf=0; nf<4; nf++){
      f32x4 sacc = (f32x4){0.f,0.f,0.f,0.f};
      #pragma unroll
      for (int kk=0; kk<4; kk++){
        bf16x8 kf = *(const bf16x8*)(Ks + (16*nf + r)*136 + kk*32 + g*8);
        sacc = __builtin_amdgcn_mfma_f32_16x16x32_bf16(qf[kk], kf, sacc, 0,0,0);
      }
      #pragma unroll
      for (int reg=0; reg<4; reg++){
        float t = fmaxf(sacc[reg] * (1.f/512.f), 0.f);
        Ps[(16*w + 4*g + reg)*72 + 16*nf + r] = f2b(t*t);
      }
    }
    // Ps rows [16w..16w+16) written & read by wave w only -> no barrier needed
    // ---- PV: O[16x256] += P[16x64] @ V[64x256] ----
    #pragma unroll
    for (int ks=0; ks<2; ks++){
      bf16x8 pa = *(const bf16x8*)(Ps + (16*w + r)*72 + ks*32 + g*8);
      #pragma unroll
      for (int nf2=0; nf2<16; nf2++){
        int e = 16*nf2 + r;
        bf16x8 vb = *(const bf16x8*)(Vt + e*64 + (((4*ks + g) ^ (e&7)) << 3));
        oacc[nf2] = __builtin_amdgcn_mfma_f32_16x16x32_bf16(pa, vb, oacc[nf2], 0,0,0);
      }
    }
    __syncthreads();
  }

  // ---- O -> LDS (overlay Vt), then coalesced u-multiply + store ----
  bf16* Os = Vt; // [64][256]
  #pragma unroll
  for (int nf2=0; nf2<16; nf2++)
    #pragma unroll
    for (int reg=0; reg<4; reg++)
      Os[(16*w + 4*g + reg)*256 + 16*nf2 + r] = f2b(oacc[nf2][reg]);
  __syncthreads();
  #pragma unroll
  for (int i=0;i<8;i++){
    int chunk = i*256 + tid;
    int row = chunk >> 5, c = chunk & 31;
    size_t grow = rowbase + n0 + row;
    bf16x8 ov  = *(const bf16x8*)(Os + row*256 + c*8);
    bf16x8 uvv = *(const bf16x8*)(uv + grow*640 + c*8);
    bf16x8 res;
    #pragma unroll
    for (int j=0;j<8;j++){
      float pv = b2f(((bf16*)&ov)[j]) * b2f(((bf16*)&uvv)[j]);
      ((bf16*)&res)[j] = f2b(pv);
    }
    *(bf16x8*)(ou + grow*D_ + c*8) = res;
  }
}

// ---------------- pooling, embedding, copyout ----------------
__global__ __launch_bounds__(256) void pool_kernel(const float* h, float* pooled) {
  int b = blockIdx.x, d = threadIdx.x;
  float s = 0.f;
  for (int t=0;t<T_;t++){
    float v = fmaxf(h[((size_t)b*T_+t)*D_ + d], 1e-6f);
    s += v*v*v;
  }
  pooled[b*D_+d] = cbrtf(s*(1.f/T_));
}

__global__ __launch_bounds__(256) void emb_kernel(const float* pooled, const float* We,
      const float* be, float* out) {
  __shared__ float pr[D_];
  __shared__ float red[256];
  int b = blockIdx.x, j = threadIdx.x;
  pr[j] = pooled[b*D_+j];
  __syncthreads();
  float acc = be[j];
  for (int kk=0;kk<D_;kk++) acc += pr[kk]*We[kk*D_+j];
  red[j] = acc*acc;
  __syncthreads();
  for (int off=128; off>0; off>>=1){
    if (j<off) red[j]+=red[j+off];
    __syncthreads();
  }
  out[b*D_+j] = acc * rsqrtf(red[0]);
}

__global__ __launch_bounds__(256) void copyout_kernel(const float* h, float* out) {
  size_t i = (size_t)blockIdx.x*256 + threadIdx.x;
  ((float4*)out)[i] = ((const float4*)h)[i];
}

extern "C" void kernel_launch(void* const* d_in, const int* in_sizes, int n_in,
                              void* d_out, int out_size, void* d_ws, size_t ws_size,
                              hipStream_t stream) {
  const float* x         = (const float*)d_in[0];
  const float* pe_scale  = (const float*)d_in[1];
  const float* W_in      = (const float*)d_in[2];
  const float* b_in      = (const float*)d_in[3];
  const float* norm_scale= (const float*)d_in[4];
  const float* W1        = (const float*)d_in[5];
  const float* b1        = (const float*)d_in[6];
  const float* gamma     = (const float*)d_in[7];
  const float* beta      = (const float*)d_in[8];
  const float* W2        = (const float*)d_in[9];
  const float* b2        = (const float*)d_in[10];
  const float* We        = (const float*)d_in[11];
  const float* be        = (const float*)d_in[12];

  char* ws = (char*)d_ws;
  float* h      = (float*)(ws);                       // 67,108,864 B
  bf16*  uv     = (bf16*)(ws + 67108864);             // 83,886,080 B
  bf16*  q      = (bf16*)(ws + 150994944);            // 16,777,216 B
  bf16*  kbuf   = (bf16*)(ws + 167772160);            // 16,777,216 B
  bf16*  ou     = (bf16*)(ws + 184549376);            // 33,554,432 B
  float* rms    = (float*)(ws + 218103808);           //    262,144 B
  float* pe_tab = (float*)(ws + 218365952);           //     49,152 B
  float* rs_tab = (float*)(ws + 218415104);           //    131,072 B
  float* rc_tab = (float*)(ws + 218546176);           //    131,072 B
  float* pooled = (float*)(ws + 218677248);           //    131,072 B

  tables_kernel<<<T_, 64, 0, stream>>>(pe_scale, pe_tab, rs_tab, rc_tab);
  embed_kernel<<<BT_/8, 256, 0, stream>>>(x, pe_tab, W_in, b_in, h);
  for (int l=0; l<L_; l++) {
    rms_kernel<<<BT_/4, 256, 0, stream>>>(h, norm_scale, l, rms);
    dim3 g1(BT_/64, 10);
    gemm1_kernel<<<g1, 256, 0, stream>>>(h, rms, W1 + (size_t)l*D_*640, b1 + l*640, uv);
    qk_kernel<<<BT_/2, 256, 0, stream>>>(uv, gamma, beta, l, rs_tab, rc_tab, q, kbuf);
    attn_mfma_kernel<<<B_*8, 256, 0, stream>>>(q, kbuf, uv, ou);
    dim3 g2(BT_/64, 4);
    gemm2_kernel<<<g2, 256, 0, stream>>>(ou, W2 + (size_t)l*D_*D_, b2 + l*D_, h);
  }
  pool_kernel<<<B_, 256, 0, stream>>>(h, pooled);
  emb_kernel<<<B_, 256, 0, stream>>>(pooled, We, be, (float*)d_out);
  copyout_kernel<<<BT_*D_/1024, 256, 0, stream>>>(h, (float*)d_out + B_*D_);
}

// Round 4
// 878.043 us; speedup vs baseline: 3.1509x; 1.6604x over previous
//
#include <hip/hip_runtime.h>
#include <hip/hip_bf16.h>

#define B_ 128
#define T_ 512
#define BIN_ 24
#define D_ 256
#define S_ 128
#define L_ 2
#define BT_ (B_*T_)

typedef __hip_bfloat16 bf16;
typedef __hip_bfloat162 bf162;
typedef __attribute__((ext_vector_type(8))) short bf16x8;
typedef __attribute__((ext_vector_type(4))) float f32x4;

__device__ __forceinline__ float b2f(bf16 x){ return __bfloat162float(x); }
__device__ __forceinline__ bf16 f2b(float x){ return __float2bfloat16(x); }

// ---------------- tables: sinusoid PE (scaled) + rope sin/cos ----------------
__global__ void tables_kernel(const float* pe_scale_ptr, float* pe_tab, float* rs, float* rc) {
  int t = blockIdx.x;      // 0..511
  int j = threadIdx.x;     // 64 threads
  float ps = pe_scale_ptr[0];
  const float LOG1E4 = 9.210340371976184f;
  if (j < 64) {
    float inv = expf(-LOG1E4 * (float)j / 64.f);   // rope: 10000^(-2j/128)
    float ang = (float)t * inv;
    rs[t*64 + j] = sinf(ang);
    rc[t*64 + j] = cosf(ang);
  }
  if (j < BIN_) {
    int jj = (j < 12) ? j : (j - 12);
    float inv = expf(-LOG1E4 * (float)jj / 11.f);  // sinusoid: num=12, denom num-1
    float ang = (float)t * inv;
    pe_tab[t*BIN_ + j] = ps * ((j < 12) ? sinf(ang) : cosf(ang));
  }
}

// ---------------- prep: W1 [2][256][640] -> W1t bf16 [2][640][256]; W2 likewise ----
__global__ __launch_bounds__(256) void prep_kernel(const float* W1, const float* W2,
                                                   bf16* W1t, bf16* W2t) {
  int idx = blockIdx.x*256 + threadIdx.x;
  if (idx < 2*256*640) {
    int l = idx / (256*640); int rem = idx % (256*640);
    int k = rem / 640; int n = rem % 640;
    W1t[(size_t)l*640*256 + n*256 + k] = f2b(W1[idx]);
  }
  if (idx < 2*256*256) {
    int l = idx >> 16; int rem = idx & 65535;
    int k = rem >> 8; int n = rem & 255;
    W2t[(size_t)l*65536 + n*256 + k] = f2b(W2[idx]);
  }
}

// ---------------- embed: h = swish((x + pe) @ W_in + b_in) ----------------
__global__ __launch_bounds__(256) void embed_kernel(const float* x, const float* pe_tab,
                const float* W_in, const float* b_in, float* h) {
  __shared__ float xr[8][BIN_];
  int tid = threadIdx.x;
  int row0 = blockIdx.x * 8;
  if (tid < 8*BIN_) {
    int r = tid / BIN_, k = tid % BIN_;
    int row = row0 + r;
    int t = row & (T_-1);
    xr[r][k] = x[(size_t)row*BIN_ + k] + pe_tab[t*BIN_ + k];
  }
  __syncthreads();
  int d = tid;
  float bi = b_in[d];
  float acc[8];
  #pragma unroll
  for (int r=0;r<8;r++) acc[r]=bi;
  #pragma unroll
  for (int k=0;k<BIN_;k++){
    float w = W_in[k*D_ + d];
    #pragma unroll
    for (int r=0;r<8;r++) acc[r] += xr[r][k]*w;
  }
  #pragma unroll
  for (int r=0;r<8;r++){
    float v = acc[r];
    h[(size_t)(row0+r)*D_ + d] = v / (1.f + expf(-v));
  }
}

// ---------------- hn: bf16 normalized h (rms * norm_scale folded in) ----------------
__global__ __launch_bounds__(256) void hn_kernel(const float* h, const float* norm_scale,
                                                 int l, bf16* hn) {
  int tid = threadIdx.x;
  int lane = tid & 63;
  size_t row = (size_t)blockIdx.x*4 + (tid>>6);
  float4 hv = *((const float4*)(h + row*D_) + lane);
  float s = hv.x*hv.x + hv.y*hv.y + hv.z*hv.z + hv.w*hv.w;
  #pragma unroll
  for (int off=32; off>0; off>>=1) s += __shfl_xor(s, off);
  float f = rsqrtf(s*(1.f/D_) + 1e-6f) * norm_scale[l];
  bf162 p0, p1;
  p0.x = f2b(hv.x*f); p0.y = f2b(hv.y*f);
  p1.x = f2b(hv.z*f); p1.y = f2b(hv.w*f);
  bf162* o = (bf162*)(hn + row*D_) + lane*2;
  o[0] = p0; o[1] = p1;
}

// ---------------- gemm1 (MFMA): uv = swish(hn @ W1 + b1), A/Bt row-major-K ----------------
__global__ __launch_bounds__(256) void gemm1_mfma(const bf16* A, const bf16* Bt,
      const float* bias, bf16* uv) {
  __shared__ bf16 As[128*72];
  __shared__ bf16 Bs[128*72];
  int tid = threadIdx.x;
  int w = tid>>6, l = tid&63, r = l&15, g = l>>4;
  int wr = w>>1, wc = w&1;
  int row0 = blockIdx.x*128, col0 = blockIdx.y*128;
  f32x4 acc[4][4];
  #pragma unroll
  for (int i=0;i<4;i++)
    #pragma unroll
    for (int j=0;j<4;j++) acc[i][j] = (f32x4){0.f,0.f,0.f,0.f};

  for (int k0=0; k0<D_; k0+=64) {
    #pragma unroll
    for (int i=0;i<4;i++){
      int id = i*256 + tid; int tr = id>>3, tc = id&7;
      *(bf16x8*)(As + tr*72 + tc*8) = *(const bf16x8*)(A  + (size_t)(row0+tr)*D_ + k0 + tc*8);
      *(bf16x8*)(Bs + tr*72 + tc*8) = *(const bf16x8*)(Bt + (size_t)(col0+tr)*D_ + k0 + tc*8);
    }
    __syncthreads();
    #pragma unroll
    for (int kk=0; kk<2; kk++){
      bf16x8 a[4], b[4];
      #pragma unroll
      for (int i=0;i<4;i++){
        a[i] = *(const bf16x8*)(As + (64*wr+16*i+r)*72 + kk*32 + g*8);
        b[i] = *(const bf16x8*)(Bs + (64*wc+16*i+r)*72 + kk*32 + g*8);
      }
      #pragma unroll
      for (int i=0;i<4;i++)
        #pragma unroll
        for (int j=0;j<4;j++)
          acc[i][j] = __builtin_amdgcn_mfma_f32_16x16x32_bf16(a[i], b[j], acc[i][j], 0,0,0);
    }
    __syncthreads();
  }
  #pragma unroll
  for (int j=0;j<4;j++){
    int gcol = col0 + 64*wc + 16*j + r;
    float bv = bias[gcol];
    #pragma unroll
    for (int i=0;i<4;i++){
      size_t grow0 = row0 + 64*wr + 16*i + 4*g;
      #pragma unroll
      for (int reg=0; reg<4; reg++){
        float v = acc[i][j][reg] + bv;
        uv[(grow0+reg)*640 + gcol] = f2b(v / (1.f + expf(-v)));
      }
    }
  }
}

// ---------------- gemm2 (MFMA): h += ou @ W2 + b2 ----------------
__global__ __launch_bounds__(256) void gemm2_mfma(const bf16* A, const bf16* Bt,
      const float* bias, float* h) {
  __shared__ bf16 As[128*72];
  __shared__ bf16 Bs[128*72];
  int tid = threadIdx.x;
  int w = tid>>6, l = tid&63, r = l&15, g = l>>4;
  int wr = w>>1, wc = w&1;
  int row0 = blockIdx.x*128, col0 = blockIdx.y*128;
  f32x4 acc[4][4];
  #pragma unroll
  for (int i=0;i<4;i++)
    #pragma unroll
    for (int j=0;j<4;j++) acc[i][j] = (f32x4){0.f,0.f,0.f,0.f};

  for (int k0=0; k0<D_; k0+=64) {
    #pragma unroll
    for (int i=0;i<4;i++){
      int id = i*256 + tid; int tr = id>>3, tc = id&7;
      *(bf16x8*)(As + tr*72 + tc*8) = *(const bf16x8*)(A  + (size_t)(row0+tr)*D_ + k0 + tc*8);
      *(bf16x8*)(Bs + tr*72 + tc*8) = *(const bf16x8*)(Bt + (size_t)(col0+tr)*D_ + k0 + tc*8);
    }
    __syncthreads();
    #pragma unroll
    for (int kk=0; kk<2; kk++){
      bf16x8 a[4], b[4];
      #pragma unroll
      for (int i=0;i<4;i++){
        a[i] = *(const bf16x8*)(As + (64*wr+16*i+r)*72 + kk*32 + g*8);
        b[i] = *(const bf16x8*)(Bs + (64*wc+16*i+r)*72 + kk*32 + g*8);
      }
      #pragma unroll
      for (int i=0;i<4;i++)
        #pragma unroll
        for (int j=0;j<4;j++)
          acc[i][j] = __builtin_amdgcn_mfma_f32_16x16x32_bf16(a[i], b[j], acc[i][j], 0,0,0);
    }
    __syncthreads();
  }
  #pragma unroll
  for (int j=0;j<4;j++){
    int gcol = col0 + 64*wc + 16*j + r;
    float bv = bias[gcol];
    #pragma unroll
    for (int i=0;i<4;i++){
      size_t grow0 = row0 + 64*wr + 16*i + 4*g;
      #pragma unroll
      for (int reg=0; reg<4; reg++){
        h[(grow0+reg)*D_ + gcol] += acc[i][j][reg] + bv;
      }
    }
  }
}

// ---------------- qk: rope(base*gamma+beta) for q and k ----------------
__global__ __launch_bounds__(256) void qk_kernel(const bf16* uv, const float* gamma, const float* beta,
      int l, const float* rs, const float* rc, bf16* q, bf16* k) {
  int tid = threadIdx.x;
  int j = tid & 127;
  size_t row = (size_t)blockIdx.x*2 + (tid>>7);
  int t = (int)(row & (T_-1));
  int j2 = j ^ 64;
  float v0 = b2f(uv[row*640 + 512 + j]);
  float v1 = b2f(uv[row*640 + 512 + j2]);
  int jm = j & 63;
  float sn = rs[t*64 + jm], cs = rc[t*64 + jm];
  float sgn = (j < 64) ? -1.f : 1.f;
  const float* g  = gamma + l*2*S_;
  const float* bt = beta  + l*2*S_;
  float xq = v0*g[j]      + bt[j];
  float pq = v1*g[j2]     + bt[j2];
  q[row*S_ + j] = f2b(xq*cs + sgn*pq*sn);
  float xk = v0*g[S_+j]   + bt[S_+j];
  float pk = v1*g[S_+j2]  + bt[S_+j2];
  k[row*S_ + j] = f2b(xk*cs + sgn*pk*sn);
}

// ---------------- attn (MFMA): ou = u * ( relu(qk^T/512)^2 @ v ) ----------------
__global__ __launch_bounds__(256) void attn_mfma_kernel(const bf16* q, const bf16* k,
      const bf16* uv, bf16* ou) {
  __shared__ char smem[59392];
  bf16* Ks = (bf16*)smem;            // [64][136]  (+8 pad -> floor-conflict b128 col reads)
  bf16* Vt = (bf16*)(smem + 17408);  // [256 e][64 m], 16B chunks XOR-swizzled by e&7; reused as Os[64][256]
  bf16* Ps = (bf16*)(smem + 50176);  // [64][72]

  int tid = threadIdx.x;
  int w = tid >> 6, l = tid & 63;
  int r = l & 15, g = l >> 4;
  int b  = blockIdx.x >> 3;
  int nt = blockIdx.x & 7;
  size_t rowbase = (size_t)b * T_;
  int n0 = nt * 64;

  bf16x8 qf[4];
  const bf16* qrow = q + (rowbase + n0 + 16*w + r) * S_ + g*8;
  #pragma unroll
  for (int kk=0; kk<4; kk++) qf[kk] = *(const bf16x8*)(qrow + kk*32);

  f32x4 oacc[16];
  #pragma unroll
  for (int i=0;i<16;i++) oacc[i] = (f32x4){0.f,0.f,0.f,0.f};

  for (int m0 = 0; m0 < T_; m0 += 64) {
    #pragma unroll
    for (int i=0;i<4;i++){
      int chunk = i*256 + tid;
      int row = chunk >> 4, c = chunk & 15;
      bf16x8 kv = *(const bf16x8*)(k + (rowbase + m0 + row)*S_ + c*8);
      *(bf16x8*)(Ks + row*136 + c*8) = kv;
    }
    #pragma unroll
    for (int i=0;i<8;i++){
      int chunk = i*256 + tid;
      int row = chunk >> 5, c = chunk & 31;
      bf16x8 vv = *(const bf16x8*)(uv + (rowbase + m0 + row)*640 + 256 + c*8);
      int mc = row >> 3, mo = row & 7;
      #pragma unroll
      for (int s=0;s<8;s++){
        int j = (s + (l & 7)) & 7;
        Vt[(8*c + j)*64 + ((mc ^ j) << 3) + mo] = ((bf16*)&vv)[j];
      }
    }
    __syncthreads();

    #pragma unroll
    for (int nf=0; nf<4; nf++){
      f32x4 sacc = (f32x4){0.f,0.f,0.f,0.f};
      #pragma unroll
      for (int kk=0; kk<4; kk++){
        bf16x8 kf = *(const bf16x8*)(Ks + (16*nf + r)*136 + kk*32 + g*8);
        sacc = __builtin_amdgcn_mfma_f32_16x16x32_bf16(qf[kk], kf, sacc, 0,0,0);
      }
      #pragma unroll
      for (int reg=0; reg<4; reg++){
        float t = fmaxf(sacc[reg] * (1.f/512.f), 0.f);
        Ps[(16*w + 4*g + reg)*72 + 16*nf + r] = f2b(t*t);
      }
    }
    #pragma unroll
    for (int ks=0; ks<2; ks++){
      bf16x8 pa = *(const bf16x8*)(Ps + (16*w + r)*72 + ks*32 + g*8);
      #pragma unroll
      for (int nf2=0; nf2<16; nf2++){
        int e = 16*nf2 + r;
        bf16x8 vb = *(const bf16x8*)(Vt + e*64 + (((4*ks + g) ^ (e&7)) << 3));
        oacc[nf2] = __builtin_amdgcn_mfma_f32_16x16x32_bf16(pa, vb, oacc[nf2], 0,0,0);
      }
    }
    __syncthreads();
  }

  bf16* Os = Vt; // [64][256]
  #pragma unroll
  for (int nf2=0; nf2<16; nf2++)
    #pragma unroll
    for (int reg=0; reg<4; reg++)
      Os[(16*w + 4*g + reg)*256 + 16*nf2 + r] = f2b(oacc[nf2][reg]);
  __syncthreads();
  #pragma unroll
  for (int i=0;i<8;i++){
    int chunk = i*256 + tid;
    int row = chunk >> 5, c = chunk & 31;
    size_t grow = rowbase + n0 + row;
    bf16x8 ov  = *(const bf16x8*)(Os + row*256 + c*8);
    bf16x8 uvv = *(const bf16x8*)(uv + grow*640 + c*8);
    bf16x8 res;
    #pragma unroll
    for (int j=0;j<8;j++){
      float pv = b2f(((bf16*)&ov)[j]) * b2f(((bf16*)&uvv)[j]);
      ((bf16*)&res)[j] = f2b(pv);
    }
    *(bf16x8*)(ou + grow*D_ + c*8) = res;
  }
}

// ---------------- pooling, embedding, copyout ----------------
__global__ __launch_bounds__(256) void pool_kernel(const float* h, float* pooled) {
  int b = blockIdx.x, d = threadIdx.x;
  float s = 0.f;
  for (int t=0;t<T_;t++){
    float v = fmaxf(h[((size_t)b*T_+t)*D_ + d], 1e-6f);
    s += v*v*v;
  }
  pooled[b*D_+d] = cbrtf(s*(1.f/T_));
}

__global__ __launch_bounds__(256) void emb_kernel(const float* pooled, const float* We,
      const float* be, float* out) {
  __shared__ float pr[D_];
  __shared__ float red[256];
  int b = blockIdx.x, j = threadIdx.x;
  pr[j] = pooled[b*D_+j];
  __syncthreads();
  float acc = be[j];
  for (int kk=0;kk<D_;kk++) acc += pr[kk]*We[kk*D_+j];
  red[j] = acc*acc;
  __syncthreads();
  for (int off=128; off>0; off>>=1){
    if (j<off) red[j]+=red[j+off];
    __syncthreads();
  }
  out[b*D_+j] = acc * rsqrtf(red[0]);
}

__global__ __launch_bounds__(256) void copyout_kernel(const float* h, float* out) {
  size_t i = (size_t)blockIdx.x*256 + threadIdx.x;
  ((float4*)out)[i] = ((const float4*)h)[i];
}

extern "C" void kernel_launch(void* const* d_in, const int* in_sizes, int n_in,
                              void* d_out, int out_size, void* d_ws, size_t ws_size,
                              hipStream_t stream) {
  const float* x         = (const float*)d_in[0];
  const float* pe_scale  = (const float*)d_in[1];
  const float* W_in      = (const float*)d_in[2];
  const float* b_in      = (const float*)d_in[3];
  const float* norm_scale= (const float*)d_in[4];
  const float* W1        = (const float*)d_in[5];
  const float* b1        = (const float*)d_in[6];
  const float* gamma     = (const float*)d_in[7];
  const float* beta      = (const float*)d_in[8];
  const float* W2        = (const float*)d_in[9];
  const float* b2        = (const float*)d_in[10];
  const float* We        = (const float*)d_in[11];
  const float* be        = (const float*)d_in[12];

  char* ws = (char*)d_ws;
  float* h      = (float*)(ws);                       // 67,108,864 B
  bf16*  uv     = (bf16*)(ws + 67108864);             // 83,886,080 B
  bf16*  q      = (bf16*)(ws + 150994944);            // 16,777,216 B
  bf16*  kbuf   = (bf16*)(ws + 167772160);            // 16,777,216 B
  bf16*  hnou   = (bf16*)(ws + 184549376);            // 33,554,432 B (hn, later ou)
  float* pe_tab = (float*)(ws + 218103808);           //     49,152 B
  float* rs_tab = (float*)(ws + 218152960);           //    131,072 B
  float* rc_tab = (float*)(ws + 218284032);           //    131,072 B
  float* pooled = (float*)(ws + 218415104);           //    131,072 B
  bf16*  W1t    = (bf16*)(ws + 218546176);            //    655,360 B
  bf16*  W2t    = (bf16*)(ws + 219201536);            //    262,144 B

  tables_kernel<<<T_, 64, 0, stream>>>(pe_scale, pe_tab, rs_tab, rc_tab);
  prep_kernel<<<1280, 256, 0, stream>>>(W1, W2, W1t, W2t);
  embed_kernel<<<BT_/8, 256, 0, stream>>>(x, pe_tab, W_in, b_in, h);
  for (int l=0; l<L_; l++) {
    hn_kernel<<<BT_/4, 256, 0, stream>>>(h, norm_scale, l, hnou);
    dim3 g1(BT_/128, 5);
    gemm1_mfma<<<g1, 256, 0, stream>>>(hnou, W1t + (size_t)l*640*D_, b1 + l*640, uv);
    qk_kernel<<<BT_/2, 256, 0, stream>>>(uv, gamma, beta, l, rs_tab, rc_tab, q, kbuf);
    attn_mfma_kernel<<<B_*8, 256, 0, stream>>>(q, kbuf, uv, hnou);
    dim3 g2(BT_/128, 2);
    gemm2_mfma<<<g2, 256, 0, stream>>>(hnou, W2t + (size_t)l*D_*D_, b2 + l*D_, h);
  }
  pool_kernel<<<B_, 256, 0, stream>>>(h, pooled);
  emb_kernel<<<B_, 256, 0, stream>>>(pooled, We, be, (float*)d_out);
  copyout_kernel<<<BT_*D_/1024, 256, 0, stream>>>(h, (float*)d_out + B_*D_);
}

// Round 5
// 486.653 us; speedup vs baseline: 5.6850x; 1.8042x over previous
//
#include <hip/hip_runtime.h>
#include <hip/hip_bf16.h>

#define B_ 128
#define T_ 512
#define BIN_ 24
#define D_ 256
#define S_ 128
#define L_ 2
#define BT_ (B_*T_)

typedef __hip_bfloat16 bf16;
typedef __hip_bfloat162 bf162;
typedef __attribute__((ext_vector_type(8))) short bf16x8;
typedef __attribute__((ext_vector_type(4))) short s16x4;
typedef __attribute__((ext_vector_type(4))) float f32x4;

__device__ __forceinline__ float b2f(bf16 x){ return __bfloat162float(x); }
__device__ __forceinline__ bf16 f2b(float x){ return __float2bfloat16(x); }

// ---------------- tables: sinusoid PE (scaled) + rope sin/cos ----------------
__global__ void tables_kernel(const float* pe_scale_ptr, float* pe_tab, float* rs, float* rc) {
  int t = blockIdx.x;      // 0..511
  int j = threadIdx.x;     // 64 threads
  float ps = pe_scale_ptr[0];
  const float LOG1E4 = 9.210340371976184f;
  if (j < 64) {
    float inv = expf(-LOG1E4 * (float)j / 64.f);   // rope: 10000^(-2j/128)
    float ang = (float)t * inv;
    rs[t*64 + j] = sinf(ang);
    rc[t*64 + j] = cosf(ang);
  }
  if (j < BIN_) {
    int jj = (j < 12) ? j : (j - 12);
    float inv = expf(-LOG1E4 * (float)jj / 11.f);  // sinusoid: num=12, denom num-1
    float ang = (float)t * inv;
    pe_tab[t*BIN_ + j] = ps * ((j < 12) ? sinf(ang) : cosf(ang));
  }
}

// ---------------- prep: W1 [2][256][640] -> W1t bf16 [2][640][256]; W2 likewise ----
__global__ __launch_bounds__(256) void prep_kernel(const float* W1, const float* W2,
                                                   bf16* W1t, bf16* W2t) {
  int idx = blockIdx.x*256 + threadIdx.x;
  if (idx < 2*256*640) {
    int l = idx / (256*640); int rem = idx % (256*640);
    int k = rem / 640; int n = rem % 640;
    W1t[(size_t)l*640*256 + n*256 + k] = f2b(W1[idx]);
  }
  if (idx < 2*256*256) {
    int l = idx >> 16; int rem = idx & 65535;
    int k = rem >> 8; int n = rem & 255;
    W2t[(size_t)l*65536 + n*256 + k] = f2b(W2[idx]);
  }
}

// ---------------- embed: h = swish((x + pe) @ W_in + b_in) ----------------
__global__ __launch_bounds__(256) void embed_kernel(const float* x, const float* pe_tab,
                const float* W_in, const float* b_in, float* h) {
  __shared__ float xr[8][BIN_];
  int tid = threadIdx.x;
  int row0 = blockIdx.x * 8;
  if (tid < 8*BIN_) {
    int r = tid / BIN_, k = tid % BIN_;
    int row = row0 + r;
    int t = row & (T_-1);
    xr[r][k] = x[(size_t)row*BIN_ + k] + pe_tab[t*BIN_ + k];
  }
  __syncthreads();
  int d = tid;
  float bi = b_in[d];
  float acc[8];
  #pragma unroll
  for (int r=0;r<8;r++) acc[r]=bi;
  #pragma unroll
  for (int k=0;k<BIN_;k++){
    float w = W_in[k*D_ + d];
    #pragma unroll
    for (int r=0;r<8;r++) acc[r] += xr[r][k]*w;
  }
  #pragma unroll
  for (int r=0;r<8;r++){
    float v = acc[r];
    h[(size_t)(row0+r)*D_ + d] = v / (1.f + expf(-v));
  }
}

// ---------------- hn: bf16 normalized h (rms * norm_scale folded in) ----------------
__global__ __launch_bounds__(256) void hn_kernel(const float* h, const float* norm_scale,
                                                 int l, bf16* hn) {
  int tid = threadIdx.x;
  int lane = tid & 63;
  size_t row = (size_t)blockIdx.x*4 + (tid>>6);
  float4 hv = *((const float4*)(h + row*D_) + lane);
  float s = hv.x*hv.x + hv.y*hv.y + hv.z*hv.z + hv.w*hv.w;
  #pragma unroll
  for (int off=32; off>0; off>>=1) s += __shfl_xor(s, off);
  float f = rsqrtf(s*(1.f/D_) + 1e-6f) * norm_scale[l];
  bf162 p0, p1;
  p0.x = f2b(hv.x*f); p0.y = f2b(hv.y*f);
  p1.x = f2b(hv.z*f); p1.y = f2b(hv.w*f);
  bf162* o = (bf162*)(hn + row*D_) + lane*2;
  o[0] = p0; o[1] = p1;
}

// ---------------- gemm1 (MFMA): [u | Vt_g | base] = swish(hn @ W1 + b1) ----------------
// u: [BT][256], Vt_g: [B][256 e][512 m] (v transposed), base: [BT][128]
__global__ __launch_bounds__(256) void gemm1_mfma(const bf16* A, const bf16* Bt,
      const float* bias, bf16* u, bf16* Vtg, bf16* basebuf) {
  __shared__ bf16 As[128*72];
  __shared__ bf16 Bs[128*72];
  int tid = threadIdx.x;
  int w = tid>>6, l = tid&63, r = l&15, g = l>>4;
  int wr = w>>1, wc = w&1;
  int row0 = blockIdx.x*128, col0 = blockIdx.y*128;
  f32x4 acc[4][4];
  #pragma unroll
  for (int i=0;i<4;i++)
    #pragma unroll
    for (int j=0;j<4;j++) acc[i][j] = (f32x4){0.f,0.f,0.f,0.f};

  for (int k0=0; k0<D_; k0+=64) {
    #pragma unroll
    for (int i=0;i<4;i++){
      int id = i*256 + tid; int tr = id>>3, tc = id&7;
      *(bf16x8*)(As + tr*72 + tc*8) = *(const bf16x8*)(A  + (size_t)(row0+tr)*D_ + k0 + tc*8);
      *(bf16x8*)(Bs + tr*72 + tc*8) = *(const bf16x8*)(Bt + (size_t)(col0+tr)*D_ + k0 + tc*8);
    }
    __syncthreads();
    #pragma unroll
    for (int kk=0; kk<2; kk++){
      bf16x8 a[4], b[4];
      #pragma unroll
      for (int i=0;i<4;i++){
        a[i] = *(const bf16x8*)(As + (64*wr+16*i+r)*72 + kk*32 + g*8);
        b[i] = *(const bf16x8*)(Bs + (64*wc+16*i+r)*72 + kk*32 + g*8);
      }
      #pragma unroll
      for (int i=0;i<4;i++)
        #pragma unroll
        for (int j=0;j<4;j++)
          acc[i][j] = __builtin_amdgcn_mfma_f32_16x16x32_bf16(a[i], b[j], acc[i][j], 0,0,0);
    }
    __syncthreads();
  }
  #pragma unroll
  for (int j=0;j<4;j++){
    int gcol = col0 + 64*wc + 16*j + r;
    float bv = bias[gcol];
    #pragma unroll
    for (int i=0;i<4;i++){
      size_t grow0 = row0 + 64*wr + 16*i + 4*g;
      if (col0 < 256) {
        #pragma unroll
        for (int reg=0; reg<4; reg++){
          float v = acc[i][j][reg] + bv;
          u[(grow0+reg)*D_ + gcol] = f2b(v / (1.f + expf(-v)));
        }
      } else if (col0 < 512) {
        // v columns: write transposed Vt_g[b][e][m], 4 consecutive m per store
        union { s16x4 s4; bf16 hh[4]; } pk;
        #pragma unroll
        for (int reg=0; reg<4; reg++){
          float v = acc[i][j][reg] + bv;
          pk.hh[reg] = f2b(v / (1.f + expf(-v)));
        }
        size_t bb = grow0 >> 9;
        int m = (int)(grow0 & 511);
        int e = gcol - 256;
        *(s16x4*)(Vtg + bb*131072 + (size_t)e*T_ + m) = pk.s4;
      } else {
        #pragma unroll
        for (int reg=0; reg<4; reg++){
          float v = acc[i][j][reg] + bv;
          basebuf[(grow0+reg)*S_ + (gcol-512)] = f2b(v / (1.f + expf(-v)));
        }
      }
    }
  }
}

// ---------------- gemm2 (MFMA): h += ou @ W2 + b2 ----------------
__global__ __launch_bounds__(256) void gemm2_mfma(const bf16* A, const bf16* Bt,
      const float* bias, float* h) {
  __shared__ bf16 As[128*72];
  __shared__ bf16 Bs[128*72];
  int tid = threadIdx.x;
  int w = tid>>6, l = tid&63, r = l&15, g = l>>4;
  int wr = w>>1, wc = w&1;
  int row0 = blockIdx.x*128, col0 = blockIdx.y*128;
  f32x4 acc[4][4];
  #pragma unroll
  for (int i=0;i<4;i++)
    #pragma unroll
    for (int j=0;j<4;j++) acc[i][j] = (f32x4){0.f,0.f,0.f,0.f};

  for (int k0=0; k0<D_; k0+=64) {
    #pragma unroll
    for (int i=0;i<4;i++){
      int id = i*256 + tid; int tr = id>>3, tc = id&7;
      *(bf16x8*)(As + tr*72 + tc*8) = *(const bf16x8*)(A  + (size_t)(row0+tr)*D_ + k0 + tc*8);
      *(bf16x8*)(Bs + tr*72 + tc*8) = *(const bf16x8*)(Bt + (size_t)(col0+tr)*D_ + k0 + tc*8);
    }
    __syncthreads();
    #pragma unroll
    for (int kk=0; kk<2; kk++){
      bf16x8 a[4], b[4];
      #pragma unroll
      for (int i=0;i<4;i++){
        a[i] = *(const bf16x8*)(As + (64*wr+16*i+r)*72 + kk*32 + g*8);
        b[i] = *(const bf16x8*)(Bs + (64*wc+16*i+r)*72 + kk*32 + g*8);
      }
      #pragma unroll
      for (int i=0;i<4;i++)
        #pragma unroll
        for (int j=0;j<4;j++)
          acc[i][j] = __builtin_amdgcn_mfma_f32_16x16x32_bf16(a[i], b[j], acc[i][j], 0,0,0);
    }
    __syncthreads();
  }
  #pragma unroll
  for (int j=0;j<4;j++){
    int gcol = col0 + 64*wc + 16*j + r;
    float bv = bias[gcol];
    #pragma unroll
    for (int i=0;i<4;i++){
      size_t grow0 = row0 + 64*wr + 16*i + 4*g;
      #pragma unroll
      for (int reg=0; reg<4; reg++){
        h[(grow0+reg)*D_ + gcol] += acc[i][j][reg] + bv;
      }
    }
  }
}

// ---------------- qk: rope(base*gamma+beta) for q and k ----------------
__global__ __launch_bounds__(256) void qk_kernel(const bf16* basebuf, const float* gamma, const float* beta,
      int l, const float* rs, const float* rc, bf16* q, bf16* k) {
  int tid = threadIdx.x;
  int j = tid & 127;
  size_t row = (size_t)blockIdx.x*2 + (tid>>7);
  int t = (int)(row & (T_-1));
  int j2 = j ^ 64;
  float v0 = b2f(basebuf[row*S_ + j]);
  float v1 = b2f(basebuf[row*S_ + j2]);
  int jm = j & 63;
  float sn = rs[t*64 + jm], cs = rc[t*64 + jm];
  float sgn = (j < 64) ? -1.f : 1.f;
  const float* g  = gamma + l*2*S_;
  const float* bt = beta  + l*2*S_;
  float xq = v0*g[j]      + bt[j];
  float pq = v1*g[j2]     + bt[j2];
  q[row*S_ + j] = f2b(xq*cs + sgn*pq*sn);
  float xk = v0*g[S_+j]   + bt[S_+j];
  float pk = v1*g[S_+j2]  + bt[S_+j2];
  k[row*S_ + j] = f2b(xk*cs + sgn*pk*sn);
}

// ---------------- attn (MFMA): ou = u * ( relu(qk^T/512)^2 @ v ) ----------------
// 512 threads / 8 waves, QBLK=128 rows per block, V pre-transposed in global (Vt_g).
__global__ __launch_bounds__(512, 4) void attn_mfma_kernel(const bf16* q, const bf16* k,
      const bf16* Vtg, const bf16* u, bf16* ou) {
  __shared__ char smem[68608];
  bf16* Ks = (bf16*)smem;            // [64][136]  (+8 pad)
  bf16* Vt = (bf16*)(smem + 17408);  // [256 e][64 m], 16B chunks XOR-swizzled by e&7
  bf16* Ps = (bf16*)(smem + 50176);  // [128][72]

  int tid = threadIdx.x;
  int w = tid >> 6, l = tid & 63;
  int r = l & 15, g = l >> 4;
  // XCD-aware mapping: batch pinned to one XCD, its 4 n-tiles temporally adjacent
  int xcd = blockIdx.x & 7, j0 = blockIdx.x >> 3;
  int b  = xcd*16 + (j0 >> 2);
  int nt = j0 & 3;
  size_t rowbase = (size_t)b * T_;
  int n0 = nt * 128;

  bf16x8 qf[4];
  const bf16* qrow = q + (rowbase + n0 + 16*w + r) * S_ + g*8;
  #pragma unroll
  for (int kk=0; kk<4; kk++) qf[kk] = *(const bf16x8*)(qrow + kk*32);

  f32x4 oacc[16];
  #pragma unroll
  for (int i=0;i<16;i++) oacc[i] = (f32x4){0.f,0.f,0.f,0.f};

  for (int m0 = 0; m0 < T_; m0 += 64) {
    // ---- stage K tile: 1024 16B chunks ----
    #pragma unroll
    for (int i=0;i<2;i++){
      int chunk = i*512 + tid;
      int row = chunk >> 4, c = chunk & 15;
      *(bf16x8*)(Ks + row*136 + c*8) =
        *(const bf16x8*)(k + (rowbase + m0 + row)*S_ + c*8);
    }
    // ---- stage Vt tile from Vt_g: 2048 16B chunks, XOR-swizzle chunk by e&7 ----
    #pragma unroll
    for (int i=0;i<4;i++){
      int chunk = i*512 + tid;
      int e = chunk >> 3, c = chunk & 7;
      *(bf16x8*)(Vt + e*64 + ((c ^ (e&7)) << 3)) =
        *(const bf16x8*)(Vtg + (size_t)b*131072 + (size_t)e*T_ + m0 + c*8);
    }
    __syncthreads();

    // ---- QK^T: rows 16w..16w+15 x cols m0..m0+63; P=relu(s/512)^2 -> Ps ----
    #pragma unroll
    for (int nf=0; nf<4; nf++){
      f32x4 sacc = (f32x4){0.f,0.f,0.f,0.f};
      #pragma unroll
      for (int kk=0; kk<4; kk++){
        bf16x8 kf = *(const bf16x8*)(Ks + (16*nf + r)*136 + kk*32 + g*8);
        sacc = __builtin_amdgcn_mfma_f32_16x16x32_bf16(qf[kk], kf, sacc, 0,0,0);
      }
      #pragma unroll
      for (int reg=0; reg<4; reg++){
        float t = fmaxf(sacc[reg] * (1.f/512.f), 0.f);
        Ps[(16*w + 4*g + reg)*72 + 16*nf + r] = f2b(t*t);
      }
    }
    // Ps rows [16w..16w+16) written & read by wave w only -> intra-wave dep
    // ---- PV: O[16x256] += P[16x64] @ V[64x256] ----
    #pragma unroll
    for (int ks=0; ks<2; ks++){
      bf16x8 pa = *(const bf16x8*)(Ps + (16*w + r)*72 + ks*32 + g*8);
      #pragma unroll
      for (int nf2=0; nf2<16; nf2++){
        int e = 16*nf2 + r;
        bf16x8 vb = *(const bf16x8*)(Vt + e*64 + (((4*ks + g) ^ (e&7)) << 3));
        oacc[nf2] = __builtin_amdgcn_mfma_f32_16x16x32_bf16(pa, vb, oacc[nf2], 0,0,0);
      }
    }
    __syncthreads();
  }

  // ---- O -> LDS (stride 264 to cut write conflicts), coalesced u-mult + store ----
  bf16* Os = (bf16*)smem; // [128][264] = 67584 B
  #pragma unroll
  for (int nf2=0; nf2<16; nf2++)
    #pragma unroll
    for (int reg=0; reg<4; reg++)
      Os[(16*w + 4*g + reg)*264 + 16*nf2 + r] = f2b(oacc[nf2][reg]);
  __syncthreads();
  #pragma unroll
  for (int i=0;i<8;i++){
    int chunk = i*512 + tid;
    int row = chunk >> 5, c = chunk & 31;
    size_t grow = rowbase + n0 + row;
    bf16x8 ov  = *(const bf16x8*)(Os + row*264 + c*8);
    bf16x8 uvv = *(const bf16x8*)(u + grow*D_ + c*8);
    bf16x8 res;
    #pragma unroll
    for (int j=0;j<8;j++){
      float pv = b2f(((bf16*)&ov)[j]) * b2f(((bf16*)&uvv)[j]);
      ((bf16*)&res)[j] = f2b(pv);
    }
    *(bf16x8*)(ou + grow*D_ + c*8) = res;
  }
}

// ---------------- pooling, embedding, copyout ----------------
__global__ __launch_bounds__(256) void pool_kernel(const float* h, float* pooled) {
  int b = blockIdx.x, d = threadIdx.x;
  float s = 0.f;
  for (int t=0;t<T_;t++){
    float v = fmaxf(h[((size_t)b*T_+t)*D_ + d], 1e-6f);
    s += v*v*v;
  }
  pooled[b*D_+d] = cbrtf(s*(1.f/T_));
}

__global__ __launch_bounds__(256) void emb_kernel(const float* pooled, const float* We,
      const float* be, float* out) {
  __shared__ float pr[D_];
  __shared__ float red[256];
  int b = blockIdx.x, j = threadIdx.x;
  pr[j] = pooled[b*D_+j];
  __syncthreads();
  float acc = be[j];
  for (int kk=0;kk<D_;kk++) acc += pr[kk]*We[kk*D_+j];
  red[j] = acc*acc;
  __syncthreads();
  for (int off=128; off>0; off>>=1){
    if (j<off) red[j]+=red[j+off];
    __syncthreads();
  }
  out[b*D_+j] = acc * rsqrtf(red[0]);
}

__global__ __launch_bounds__(256) void copyout_kernel(const float* h, float* out) {
  size_t i = (size_t)blockIdx.x*256 + threadIdx.x;
  ((float4*)out)[i] = ((const float4*)h)[i];
}

extern "C" void kernel_launch(void* const* d_in, const int* in_sizes, int n_in,
                              void* d_out, int out_size, void* d_ws, size_t ws_size,
                              hipStream_t stream) {
  const float* x         = (const float*)d_in[0];
  const float* pe_scale  = (const float*)d_in[1];
  const float* W_in      = (const float*)d_in[2];
  const float* b_in      = (const float*)d_in[3];
  const float* norm_scale= (const float*)d_in[4];
  const float* W1        = (const float*)d_in[5];
  const float* b1        = (const float*)d_in[6];
  const float* gamma     = (const float*)d_in[7];
  const float* beta      = (const float*)d_in[8];
  const float* W2        = (const float*)d_in[9];
  const float* b2        = (const float*)d_in[10];
  const float* We        = (const float*)d_in[11];
  const float* be        = (const float*)d_in[12];

  char* ws = (char*)d_ws;
  float* h      = (float*)(ws);                       // 67,108,864 B
  bf16*  u      = (bf16*)(ws + 67108864);             // 33,554,432 B
  bf16*  Vtg    = (bf16*)(ws + 100663296);            // 33,554,432 B
  bf16*  basebuf= (bf16*)(ws + 134217728);            // 16,777,216 B
  bf16*  q      = (bf16*)(ws + 150994944);            // 16,777,216 B
  bf16*  kbuf   = (bf16*)(ws + 167772160);            // 16,777,216 B
  bf16*  hnou   = (bf16*)(ws + 184549376);            // 33,554,432 B (hn, later ou)
  float* pe_tab = (float*)(ws + 218103808);           //     49,152 B
  float* rs_tab = (float*)(ws + 218152960);           //    131,072 B
  float* rc_tab = (float*)(ws + 218284032);           //    131,072 B
  float* pooled = (float*)(ws + 218415104);           //    131,072 B
  bf16*  W1t    = (bf16*)(ws + 218546176);            //    655,360 B
  bf16*  W2t    = (bf16*)(ws + 219201536);            //    262,144 B

  tables_kernel<<<T_, 64, 0, stream>>>(pe_scale, pe_tab, rs_tab, rc_tab);
  prep_kernel<<<1280, 256, 0, stream>>>(W1, W2, W1t, W2t);
  embed_kernel<<<BT_/8, 256, 0, stream>>>(x, pe_tab, W_in, b_in, h);
  for (int l=0; l<L_; l++) {
    hn_kernel<<<BT_/4, 256, 0, stream>>>(h, norm_scale, l, hnou);
    dim3 g1(BT_/128, 5);
    gemm1_mfma<<<g1, 256, 0, stream>>>(hnou, W1t + (size_t)l*640*D_, b1 + l*640, u, Vtg, basebuf);
    qk_kernel<<<BT_/2, 256, 0, stream>>>(basebuf, gamma, beta, l, rs_tab, rc_tab, q, kbuf);
    attn_mfma_kernel<<<B_*4, 512, 0, stream>>>(q, kbuf, Vtg, u, hnou);
    dim3 g2(BT_/128, 2);
    gemm2_mfma<<<g2, 256, 0, stream>>>(hnou, W2t + (size_t)l*D_*D_, b2 + l*D_, h);
  }
  pool_kernel<<<B_, 256, 0, stream>>>(h, pooled);
  emb_kernel<<<B_, 256, 0, stream>>>(pooled, We, be, (float*)d_out);
  copyout_kernel<<<BT_*D_/1024, 256, 0, stream>>>(h, (float*)d_out + B_*D_);
}